// Round 2
// baseline (1674.979 us; speedup 1.0000x reference)
//
#include <hip/hip_runtime.h>
#include <hip/hip_bf16.h>

// All inputs and the output are FP32 (per reference source dtypes).

// ---------------- LayerNorm: x (4096,1024) fp32 -> xn fp32 ----------------
__global__ __launch_bounds__(256) void ln_kernel(const float* __restrict__ x,
                                                 const float* __restrict__ g,
                                                 const float* __restrict__ beta,
                                                 float* __restrict__ xn) {
  int row = blockIdx.x;
  int t = threadIdx.x;
  const float* xr = x + (size_t)row * 1024;
  float4 v = *(const float4*)(xr + t * 4);
  float s = v.x + v.y + v.z + v.w;
  float ss = v.x * v.x + v.y * v.y + v.z * v.z + v.w * v.w;
  #pragma unroll
  for (int m = 1; m < 64; m <<= 1) {
    s  += __shfl_xor(s, m);
    ss += __shfl_xor(ss, m);
  }
  __shared__ float sbuf[4], ssbuf[4];
  int wave = t >> 6, lane = t & 63;
  if (lane == 0) { sbuf[wave] = s; ssbuf[wave] = ss; }
  __syncthreads();
  s  = sbuf[0] + sbuf[1] + sbuf[2] + sbuf[3];
  ss = ssbuf[0] + ssbuf[1] + ssbuf[2] + ssbuf[3];
  float mean = s * (1.0f / 1024.0f);
  float var  = ss * (1.0f / 1024.0f) - mean * mean;
  float rstd = 1.0f / sqrtf(var + 1e-5f);
  float4 gv = *(const float4*)(g + t * 4);
  float4 bv = *(const float4*)(beta + t * 4);
  float4 o;
  o.x = (v.x - mean) * rstd * gv.x + bv.x;
  o.y = (v.y - mean) * rstd * gv.y + bv.y;
  o.z = (v.z - mean) * rstd * gv.z + bv.z;
  o.w = (v.w - mean) * rstd * gv.w + bv.w;
  *(float4*)(xn + (size_t)row * 1024 + t * 4) = o;
}

// ---------------- GEMM: C(M x N) = A(M x K) @ W(N x K)^T + bias ----------------
// A fp32 (row stride lda), W fp32 row-major N x K, bias fp32.
// SLAB: A column slab offset = (n0/1024)*1024 (block-diagonal second projection).
// BM=BN=128, BK=8, 256 threads, 8x8 per thread.
#define GBM 128
#define GBN 128
#define GBK 8
template<bool SLAB>
__global__ __launch_bounds__(256) void gemm_bt(const float* __restrict__ A, int lda,
                                               const float* __restrict__ W,
                                               const float* __restrict__ bias,
                                               float* __restrict__ C,
                                               int ldc, int K) {
  __shared__ float As[GBK][GBM];
  __shared__ float Ws[GBK][GBN];
  int n0 = blockIdx.x * GBN, m0 = blockIdx.y * GBM;
  int aoff = SLAB ? ((n0 >> 10) << 10) : 0;
  int tid = threadIdx.x, tx = tid & 15, ty = tid >> 4;
  int lm = tid >> 1, lk = (tid & 1) * 4;
  float acc[8][8] = {};
  const float* Ap = A + (size_t)(m0 + lm) * lda + aoff + lk;
  const float* Wp = W + (size_t)(n0 + lm) * K + lk;
  for (int k0 = 0; k0 < K; k0 += GBK) {
    float4 av = *(const float4*)(Ap + k0);
    float4 wv = *(const float4*)(Wp + k0);
    __syncthreads();  // previous iteration's compute must finish before overwrite
    As[lk + 0][lm] = av.x; As[lk + 1][lm] = av.y;
    As[lk + 2][lm] = av.z; As[lk + 3][lm] = av.w;
    Ws[lk + 0][lm] = wv.x; Ws[lk + 1][lm] = wv.y;
    Ws[lk + 2][lm] = wv.z; Ws[lk + 3][lm] = wv.w;
    __syncthreads();
    #pragma unroll
    for (int kk = 0; kk < GBK; kk++) {
      float a[8], b[8];
      #pragma unroll
      for (int i = 0; i < 8; i++) a[i] = As[kk][ty * 8 + i];
      #pragma unroll
      for (int j = 0; j < 8; j++) b[j] = Ws[kk][tx * 8 + j];
      #pragma unroll
      for (int i = 0; i < 8; i++)
        #pragma unroll
        for (int j = 0; j < 8; j++)
          acc[i][j] += a[i] * b[j];
    }
  }
  int r0 = m0 + ty * 8, c0 = n0 + tx * 8;
  #pragma unroll
  for (int i = 0; i < 8; i++) {
    size_t ro = (size_t)(r0 + i) * ldc + c0;
    #pragma unroll
    for (int j = 0; j < 8; j++) {
      C[ro + j] = acc[i][j] + bias[c0 + j];
    }
  }
}

// ---------------- RoPE in-place on qkv cols [0,2048): interleaved pairs ----------------
__global__ __launch_bounds__(256) void rope_kernel(float* __restrict__ qkv) {
  int idx = blockIdx.x * 256 + threadIdx.x;      // 4096*1024 pairs (q and k slabs)
  int row = idx >> 10;
  int p = idx & 1023;
  int c = p >> 9;       // 0 = q slab, 1 = k slab
  int i = p & 511;      // pair index within dim
  int pos = row & 2047; // sequence position
  float* base = qkv + (size_t)row * 3072 + c * 1024 + 2 * i;
  // inv_freq = 10000^(-2i/1024); fp64 angle for accuracy at pos up to 2047
  double ifreq = exp2(-(double)(2 * i) * (13.287712379549449 / 1024.0));
  double ang = (double)pos * ifreq;
  double sn, cs;
  sincos(ang, &sn, &cs);
  float x1 = base[0], x2 = base[1];
  float fs = (float)sn, fc = (float)cs;
  base[0] = x1 * fc - x2 * fs;
  base[1] = x2 * fc + x1 * fs;
}

// ---------------- Flash attention (fp32): qkv2 (4096,3072) -> out (4096,1024) ----------------
// q cols [0,1024), k [1024,2048), v [2048,3072); head h = cols [h*64,(h+1)*64).
__global__ __launch_bounds__(256) void attn_kernel(const float* __restrict__ qkv2,
                                                   const float* __restrict__ mask,
                                                   float* __restrict__ out) {
  __shared__ float Qs[64][65];
  __shared__ float Ks[64][65];
  __shared__ float Vs[64][65];
  __shared__ float Ps[64][65];
  int qt = blockIdx.x, h = blockIdx.y, bb = blockIdx.z;
  int tid = threadIdx.x;
  int tx = tid & 15, ty = tid >> 4;
  int lr = tid >> 2, ld0 = (tid & 3) * 16;
  { // load Q tile
    const float* src = qkv2 + ((size_t)(bb * 2048 + qt * 64 + lr)) * 3072 + h * 64 + ld0;
    #pragma unroll
    for (int u = 0; u < 4; u++) {
      float4 v = *(const float4*)(src + u * 4);
      Qs[lr][ld0 + u * 4 + 0] = v.x; Qs[lr][ld0 + u * 4 + 1] = v.y;
      Qs[lr][ld0 + u * 4 + 2] = v.z; Qs[lr][ld0 + u * 4 + 3] = v.w;
    }
  }
  float m_i[4], l_i[4], acc[4][4];
  #pragma unroll
  for (int i = 0; i < 4; i++) {
    m_i[i] = -INFINITY; l_i[i] = 0.f;
    #pragma unroll
    for (int j = 0; j < 4; j++) acc[i][j] = 0.f;
  }
  const float scale = 0.125f;  // 1/sqrt(64)
  for (int kt = 0; kt < 32; kt++) {
    { // load K, V tiles
      const float* ks = qkv2 + ((size_t)(bb * 2048 + kt * 64 + lr)) * 3072 + 1024 + h * 64 + ld0;
      #pragma unroll
      for (int u = 0; u < 4; u++) {
        float4 v = *(const float4*)(ks + u * 4);
        Ks[lr][ld0 + u * 4 + 0] = v.x; Ks[lr][ld0 + u * 4 + 1] = v.y;
        Ks[lr][ld0 + u * 4 + 2] = v.z; Ks[lr][ld0 + u * 4 + 3] = v.w;
        float4 w = *(const float4*)(ks + 1024 + u * 4);
        Vs[lr][ld0 + u * 4 + 0] = w.x; Vs[lr][ld0 + u * 4 + 1] = w.y;
        Vs[lr][ld0 + u * 4 + 2] = w.z; Vs[lr][ld0 + u * 4 + 3] = w.w;
      }
    }
    __syncthreads();
    float s[4][4] = {};
    for (int d = 0; d < 64; d++) {
      float q0 = Qs[ty * 4 + 0][d], q1 = Qs[ty * 4 + 1][d];
      float q2 = Qs[ty * 4 + 2][d], q3 = Qs[ty * 4 + 3][d];
      float k0 = Ks[tx * 4 + 0][d], k1 = Ks[tx * 4 + 1][d];
      float k2 = Ks[tx * 4 + 2][d], k3 = Ks[tx * 4 + 3][d];
      s[0][0] += q0 * k0; s[0][1] += q0 * k1; s[0][2] += q0 * k2; s[0][3] += q0 * k3;
      s[1][0] += q1 * k0; s[1][1] += q1 * k1; s[1][2] += q1 * k2; s[1][3] += q1 * k3;
      s[2][0] += q2 * k0; s[2][1] += q2 * k1; s[2][2] += q2 * k2; s[2][3] += q2 * k3;
      s[3][0] += q3 * k0; s[3][1] += q3 * k1; s[3][2] += q3 * k2; s[3][3] += q3 * k3;
    }
    const float* mrow = mask +
        ((size_t)bb * 2048 + qt * 64 + ty * 4) * 2048 + kt * 64 + tx * 4;
    #pragma unroll
    for (int i = 0; i < 4; i++) {
      float4 mu = *(const float4*)(mrow + (size_t)i * 2048);
      s[i][0] = s[i][0] * scale + mu.x;
      s[i][1] = s[i][1] * scale + mu.y;
      s[i][2] = s[i][2] * scale + mu.z;
      s[i][3] = s[i][3] * scale + mu.w;
    }
    #pragma unroll
    for (int i = 0; i < 4; i++) {
      float t = fmaxf(fmaxf(s[i][0], s[i][1]), fmaxf(s[i][2], s[i][3]));
      t = fmaxf(t, __shfl_xor(t, 1)); t = fmaxf(t, __shfl_xor(t, 2));
      t = fmaxf(t, __shfl_xor(t, 4)); t = fmaxf(t, __shfl_xor(t, 8));
      float mn = fmaxf(m_i[i], t);
      float alpha = expf(m_i[i] - mn);   // expf(-inf)=0 on first tile
      float p0 = expf(s[i][0] - mn), p1 = expf(s[i][1] - mn);
      float p2 = expf(s[i][2] - mn), p3 = expf(s[i][3] - mn);
      float rs = p0 + p1 + p2 + p3;
      rs += __shfl_xor(rs, 1); rs += __shfl_xor(rs, 2);
      rs += __shfl_xor(rs, 4); rs += __shfl_xor(rs, 8);
      l_i[i] = l_i[i] * alpha + rs;
      m_i[i] = mn;
      acc[i][0] *= alpha; acc[i][1] *= alpha; acc[i][2] *= alpha; acc[i][3] *= alpha;
      Ps[ty * 4 + i][tx * 4 + 0] = p0; Ps[ty * 4 + i][tx * 4 + 1] = p1;
      Ps[ty * 4 + i][tx * 4 + 2] = p2; Ps[ty * 4 + i][tx * 4 + 3] = p3;
    }
    __syncthreads();
    for (int j = 0; j < 64; j++) {
      float p0 = Ps[ty * 4 + 0][j], p1 = Ps[ty * 4 + 1][j];
      float p2 = Ps[ty * 4 + 2][j], p3 = Ps[ty * 4 + 3][j];
      float v0 = Vs[j][tx * 4 + 0], v1 = Vs[j][tx * 4 + 1];
      float v2 = Vs[j][tx * 4 + 2], v3 = Vs[j][tx * 4 + 3];
      acc[0][0] += p0 * v0; acc[0][1] += p0 * v1; acc[0][2] += p0 * v2; acc[0][3] += p0 * v3;
      acc[1][0] += p1 * v0; acc[1][1] += p1 * v1; acc[1][2] += p1 * v2; acc[1][3] += p1 * v3;
      acc[2][0] += p2 * v0; acc[2][1] += p2 * v1; acc[2][2] += p2 * v2; acc[2][3] += p2 * v3;
      acc[3][0] += p3 * v0; acc[3][1] += p3 * v1; acc[3][2] += p3 * v2; acc[3][3] += p3 * v3;
    }
    __syncthreads();
  }
  #pragma unroll
  for (int i = 0; i < 4; i++) {
    float inv = 1.0f / l_i[i];
    float* op = out + ((size_t)(bb * 2048 + qt * 64 + ty * 4 + i)) * 1024 + h * 64 + tx * 4;
    op[0] = acc[i][0] * inv; op[1] = acc[i][1] * inv;
    op[2] = acc[i][2] * inv; op[3] = acc[i][3] * inv;
  }
}

extern "C" void kernel_launch(void* const* d_in, const int* in_sizes, int n_in,
                              void* d_out, int out_size, void* d_ws, size_t ws_size,
                              hipStream_t stream) {
  const float* x     = (const float*)d_in[0];
  const float* mask  = (const float*)d_in[1];
  const float* ln_g  = (const float*)d_in[2];
  const float* ln_b  = (const float*)d_in[3];
  const float* w_qkv = (const float*)d_in[4];
  const float* b_qkv = (const float*)d_in[5];
  const float* in_w  = (const float*)d_in[6];
  const float* in_b  = (const float*)d_in[7];
  const float* out_w = (const float*)d_in[8];
  const float* out_b = (const float*)d_in[9];
  float* out = (float*)d_out;
  char* ws = (char*)d_ws;

  // fp32 workspace layout, peak 100.7 MB:
  //   qkv  [0, 50331648)            4096*3072 fp32
  //   xn   [50331648, 67108864)     4096*1024 fp32 (dead after gemm1)
  //   qkv2 [50331648, 100663296)    4096*3072 fp32 (overwrites dead xn)
  //   attn_out [0, 16777216)        reuses dead qkv
  float* qkv      = (float*)ws;
  float* xn       = (float*)(ws + 50331648ull);
  float* qkv2     = (float*)(ws + 50331648ull);
  float* attn_out = (float*)ws;

  ln_kernel<<<4096, 256, 0, stream>>>(x, ln_g, ln_b, xn);
  gemm_bt<false><<<dim3(24, 32), 256, 0, stream>>>(
      xn, 1024, w_qkv, b_qkv, qkv, 3072, 1024);
  rope_kernel<<<16384, 256, 0, stream>>>(qkv);
  gemm_bt<true><<<dim3(24, 32), 256, 0, stream>>>(
      qkv, 3072, in_w, in_b, qkv2, 3072, 1024);
  attn_kernel<<<dim3(32, 16, 2), 256, 0, stream>>>(qkv2, mask, attn_out);
  gemm_bt<false><<<dim3(8, 32), 256, 0, stream>>>(
      attn_out, 1024, out_w, out_b, out, 1024, 1024);
}

// Round 3
// 558.236 us; speedup vs baseline: 3.0005x; 3.0005x over previous
//
#include <hip/hip_runtime.h>

using u16 = unsigned short;
typedef __attribute__((ext_vector_type(8))) short short8;
typedef __attribute__((ext_vector_type(4))) float f32x4;

__device__ __forceinline__ u16 f2b(float f) {  // RNE fp32->bf16
  union { float f; unsigned u; } v; v.f = f;
  unsigned r = v.u + 0x7fffu + ((v.u >> 16) & 1u);
  return (u16)(r >> 16);
}
__device__ __forceinline__ float b2f(u16 u) {
  union { unsigned u; float f; } v; v.u = ((unsigned)u) << 16; return v.f;
}

// ---------------- fp32 -> bf16 pack (weights) ----------------
__global__ __launch_bounds__(256) void pack_bf16(const float* __restrict__ in,
                                                 u16* __restrict__ out, int n4) {
  int i = blockIdx.x * 256 + threadIdx.x;
  if (i >= n4) return;
  float4 v = ((const float4*)in)[i];
  uint2 o;
  o.x = (unsigned)f2b(v.x) | ((unsigned)f2b(v.y) << 16);
  o.y = (unsigned)f2b(v.z) | ((unsigned)f2b(v.w) << 16);
  ((uint2*)out)[i] = o;
}

// ---------------- LayerNorm: x fp32 (4096,1024) -> xn bf16 ----------------
__global__ __launch_bounds__(256) void ln_pack(const float* __restrict__ x,
                                               const float* __restrict__ g,
                                               const float* __restrict__ beta,
                                               u16* __restrict__ xn) {
  int row = blockIdx.x;
  int t = threadIdx.x;
  const float* xr = x + (size_t)row * 1024;
  float4 v = *(const float4*)(xr + t * 4);
  float s = v.x + v.y + v.z + v.w;
  float ss = v.x * v.x + v.y * v.y + v.z * v.z + v.w * v.w;
  #pragma unroll
  for (int m = 1; m < 64; m <<= 1) {
    s  += __shfl_xor(s, m);
    ss += __shfl_xor(ss, m);
  }
  __shared__ float sbuf[4], ssbuf[4];
  int wave = t >> 6, lane = t & 63;
  if (lane == 0) { sbuf[wave] = s; ssbuf[wave] = ss; }
  __syncthreads();
  s  = sbuf[0] + sbuf[1] + sbuf[2] + sbuf[3];
  ss = ssbuf[0] + ssbuf[1] + ssbuf[2] + ssbuf[3];
  float mean = s * (1.0f / 1024.0f);
  float var  = ss * (1.0f / 1024.0f) - mean * mean;
  float rstd = 1.0f / sqrtf(var + 1e-5f);
  float4 gv = *(const float4*)(g + t * 4);
  float4 bv = *(const float4*)(beta + t * 4);
  uint2 o;
  o.x = (unsigned)f2b((v.x - mean) * rstd * gv.x + bv.x) |
        ((unsigned)f2b((v.y - mean) * rstd * gv.y + bv.y) << 16);
  o.y = (unsigned)f2b((v.z - mean) * rstd * gv.z + bv.z) |
        ((unsigned)f2b((v.w - mean) * rstd * gv.w + bv.w) << 16);
  *(uint2*)(xn + (size_t)row * 1024 + t * 4) = o;
}

// ---------------- bf16 MFMA GEMM: C(MxN) = A(MxK) @ W(NxK)^T + bias ----------------
// 128x128 tile, BK=64, 256 thr / 4 waves, each wave 64x64 via 4x4 MFMA 16x16x32.
// LDS row stride 72 (16B-aligned rows, staggered banks).
// SLAB: A column offset (n0/1024)*1024 (block-diagonal second projection).
template<bool SLAB, bool OUT_BF16>
__global__ __launch_bounds__(256) void gemm_mfma(const u16* __restrict__ A, int lda,
                                                 const u16* __restrict__ W,
                                                 const float* __restrict__ bias,
                                                 float* __restrict__ Cf,
                                                 u16* __restrict__ Cb,
                                                 int ldc, int K) {
  __shared__ u16 As[128 * 72];
  __shared__ u16 Bs[128 * 72];
  int n0 = blockIdx.x * 128, m0 = blockIdx.y * 128;
  int aoff = SLAB ? ((n0 >> 10) << 10) : 0;
  int tid = threadIdx.x;
  int lane = tid & 63, l15 = lane & 15, quad = lane >> 4;
  int w = tid >> 6, mw = w & 1, nw = w >> 1;
  const u16* Abase = A + (size_t)m0 * lda + aoff;
  const u16* Wbase = W + (size_t)n0 * K;
  f32x4 acc[4][4];
  #pragma unroll
  for (int i = 0; i < 4; i++)
    #pragma unroll
    for (int j = 0; j < 4; j++) acc[i][j] = (f32x4){0.f, 0.f, 0.f, 0.f};

  for (int k0 = 0; k0 < K; k0 += 64) {
    uint4 areg[4], wreg[4];
    #pragma unroll
    for (int i = 0; i < 4; i++) {
      int chunk = i * 256 + tid;
      int row = chunk >> 3, cc = chunk & 7;
      areg[i] = *(const uint4*)(Abase + (size_t)row * lda + k0 + cc * 8);
      wreg[i] = *(const uint4*)(Wbase + (size_t)row * K + k0 + cc * 8);
    }
    __syncthreads();  // previous iteration's fragment reads done
    #pragma unroll
    for (int i = 0; i < 4; i++) {
      int chunk = i * 256 + tid;
      int row = chunk >> 3, cc = chunk & 7;
      *(uint4*)&As[row * 72 + cc * 8] = areg[i];
      *(uint4*)&Bs[row * 72 + cc * 8] = wreg[i];
    }
    __syncthreads();
    #pragma unroll
    for (int kk = 0; kk < 64; kk += 32) {
      short8 af[4], bfr[4];
      #pragma unroll
      for (int mt = 0; mt < 4; mt++)
        af[mt] = *(const short8*)&As[(mw * 64 + mt * 16 + l15) * 72 + kk + quad * 8];
      #pragma unroll
      for (int nt = 0; nt < 4; nt++)
        bfr[nt] = *(const short8*)&Bs[(nw * 64 + nt * 16 + l15) * 72 + kk + quad * 8];
      #pragma unroll
      for (int mt = 0; mt < 4; mt++)
        #pragma unroll
        for (int nt = 0; nt < 4; nt++)
          acc[mt][nt] = __builtin_amdgcn_mfma_f32_16x16x32_bf16(
              af[mt], bfr[nt], acc[mt][nt], 0, 0, 0);
    }
  }
  int mb = m0 + mw * 64, nb = n0 + nw * 64;
  float bv[4];
  #pragma unroll
  for (int nt = 0; nt < 4; nt++) bv[nt] = bias[nb + nt * 16 + l15];
  #pragma unroll
  for (int mt = 0; mt < 4; mt++)
    #pragma unroll
    for (int nt = 0; nt < 4; nt++)
      #pragma unroll
      for (int reg = 0; reg < 4; reg++) {
        // C/D layout: row = quad*4+reg, col = lane&15  [verified m89/m91]
        int row = mb + mt * 16 + quad * 4 + reg;
        int col = nb + nt * 16 + l15;
        float val = acc[mt][nt][reg] + bv[nt];
        if (OUT_BF16) Cb[(size_t)row * ldc + col] = f2b(val);
        else          Cf[(size_t)row * ldc + col] = val;
      }
}

// ---------------- RoPE in-place on qkv bf16 cols [0,2048): interleaved pairs ----------------
__global__ __launch_bounds__(256) void rope_b(u16* __restrict__ qkv) {
  int idx = blockIdx.x * 256 + threadIdx.x;  // 4096*1024 pairs
  int row = idx >> 10;
  int p = idx & 1023;
  int c = p >> 9;       // 0=q, 1=k
  int i = p & 511;
  int pos = row & 2047;
  u16* base = qkv + (size_t)row * 3072 + c * 1024 + 2 * i;
  double ifreq = exp2(-(double)(2 * i) * (13.287712379549449 / 1024.0));
  double ang = (double)pos * ifreq;
  double sn, cs;
  sincos(ang, &sn, &cs);
  unsigned pr = *(unsigned*)base;
  float x1 = b2f((u16)(pr & 0xffff)), x2 = b2f((u16)(pr >> 16));
  float fc = (float)cs, fs = (float)sn;
  unsigned o = (unsigned)f2b(x1 * fc - x2 * fs) | ((unsigned)f2b(x2 * fc + x1 * fs) << 16);
  *(unsigned*)base = o;
}

// ---------------- V transpose: qkv2 v-cols -> vT[bb][h][d][s] bf16 ----------------
__global__ __launch_bounds__(256) void transpose_v(const u16* __restrict__ qkv2,
                                                   u16* __restrict__ vT) {
  __shared__ u16 T[64 * 72];
  int st = blockIdx.x, h = blockIdx.y, bb = blockIdx.z;
  int t = threadIdx.x;
  int r = t >> 2, c0 = (t & 3) * 16;
  const u16* src = qkv2 + (size_t)(bb * 2048 + st * 64 + r) * 3072 + 2048 + h * 64 + c0;
  *(uint4*)&T[r * 72 + c0]     = *(const uint4*)src;
  *(uint4*)&T[r * 72 + c0 + 8] = *(const uint4*)(src + 8);
  __syncthreads();
  int d = t >> 2, s0 = (t & 3) * 16;
  u16 tmp[16];
  #pragma unroll
  for (int j = 0; j < 16; j++) tmp[j] = T[(s0 + j) * 72 + d];
  u16* dst = vT + ((size_t)((bb * 16 + h) * 64 + d)) * 2048 + st * 64 + s0;
  *(uint4*)dst       = *(uint4*)&tmp[0];
  *(uint4*)(dst + 8) = *(uint4*)&tmp[8];
}

// ---------------- Flash attention, bf16 MFMA ----------------
// Block: (h, qt, bb); 4 waves, wave w owns Q rows [qt*64+w*16, +16).
// S strip per wave: 16x64 in C-layout; P -> LDS -> A-layout for PV (m120 pattern).
__global__ __launch_bounds__(256) void attn_mfma(const u16* __restrict__ qkv2,
                                                 const u16* __restrict__ vT,
                                                 const float* __restrict__ mask,
                                                 u16* __restrict__ attn_out) {
  __shared__ u16 Ks[64 * 72];
  __shared__ u16 Vs[64 * 72];
  __shared__ u16 Ps[64 * 72];  // Q tile at start, then P tiles (strip-local per wave)
  int h = blockIdx.x, qt = blockIdx.y, bb = blockIdx.z;
  int tid = threadIdx.x;
  int lane = tid & 63, l15 = lane & 15, quad = lane >> 4;
  int w = tid >> 6;
  {  // stage Q (each wave covers exactly its own strip rows t>>2 in [16w,16w+16))
    int r = tid >> 2, c0 = (tid & 3) * 16;
    const u16* src = qkv2 + (size_t)(bb * 2048 + qt * 64 + r) * 3072 + h * 64 + c0;
    *(uint4*)&Ps[r * 72 + c0]     = *(const uint4*)src;
    *(uint4*)&Ps[r * 72 + c0 + 8] = *(const uint4*)(src + 8);
  }
  // A-operand frags of Q (loop-invariant), strip-local -> no barrier needed
  short8 aq0 = *(const short8*)&Ps[(w * 16 + l15) * 72 + quad * 8];
  short8 aq1 = *(const short8*)&Ps[(w * 16 + l15) * 72 + 32 + quad * 8];
  float m_i[4], l_i[4];
  f32x4 acc[4];
  #pragma unroll
  for (int i = 0; i < 4; i++) {
    m_i[i] = -INFINITY; l_i[i] = 0.f;
    acc[i] = (f32x4){0.f, 0.f, 0.f, 0.f};
  }
  const float scale = 0.125f;
  for (int kt = 0; kt < 32; kt++) {
    {  // stage K tile and V^T tile
      int r = tid >> 2, c0 = (tid & 3) * 16;
      const u16* ksrc = qkv2 + (size_t)(bb * 2048 + kt * 64 + r) * 3072 + 1024 + h * 64 + c0;
      *(uint4*)&Ks[r * 72 + c0]     = *(const uint4*)ksrc;
      *(uint4*)&Ks[r * 72 + c0 + 8] = *(const uint4*)(ksrc + 8);
      const u16* vsrc = vT + ((size_t)((bb * 16 + h) * 64 + r)) * 2048 + kt * 64 + c0;
      *(uint4*)&Vs[r * 72 + c0]     = *(const uint4*)vsrc;
      *(uint4*)&Vs[r * 72 + c0 + 8] = *(const uint4*)(vsrc + 8);
    }
    __syncthreads();
    // S = Q K^T : 4 ntiles x 2 k-halves
    f32x4 s[4];
    #pragma unroll
    for (int nt = 0; nt < 4; nt++) {
      short8 bk0 = *(const short8*)&Ks[(nt * 16 + l15) * 72 + quad * 8];
      short8 bk1 = *(const short8*)&Ks[(nt * 16 + l15) * 72 + 32 + quad * 8];
      f32x4 z = (f32x4){0.f, 0.f, 0.f, 0.f};
      z = __builtin_amdgcn_mfma_f32_16x16x32_bf16(aq0, bk0, z, 0, 0, 0);
      s[nt] = __builtin_amdgcn_mfma_f32_16x16x32_bf16(aq1, bk1, z, 0, 0, 0);
    }
    // mask + online softmax; rows r = quad*4+reg (strip-local)
    const float* mrow = mask + ((size_t)bb * 2048 + qt * 64 + w * 16 + quad * 4) * 2048
                        + (size_t)kt * 64 + l15;
    float alpha[4];
    #pragma unroll
    for (int reg = 0; reg < 4; reg++) {
      float sv[4], mx = -INFINITY;
      #pragma unroll
      for (int nt = 0; nt < 4; nt++) {
        sv[nt] = s[nt][reg] * scale + mrow[(size_t)reg * 2048 + nt * 16];
        mx = fmaxf(mx, sv[nt]);
      }
      mx = fmaxf(mx, __shfl_xor(mx, 1)); mx = fmaxf(mx, __shfl_xor(mx, 2));
      mx = fmaxf(mx, __shfl_xor(mx, 4)); mx = fmaxf(mx, __shfl_xor(mx, 8));
      float mn = fmaxf(m_i[reg], mx);
      alpha[reg] = __expf(m_i[reg] - mn);   // 0 on first tile
      float rs = 0.f;
      #pragma unroll
      for (int nt = 0; nt < 4; nt++) {
        float e = __expf(sv[nt] - mn);
        rs += e;
        Ps[(w * 16 + quad * 4 + reg) * 72 + nt * 16 + l15] = f2b(e);
      }
      rs += __shfl_xor(rs, 1); rs += __shfl_xor(rs, 2);
      rs += __shfl_xor(rs, 4); rs += __shfl_xor(rs, 8);
      l_i[reg] = l_i[reg] * alpha[reg] + rs;
      m_i[reg] = mn;
    }
    #pragma unroll
    for (int dt = 0; dt < 4; dt++)
      #pragma unroll
      for (int reg = 0; reg < 4; reg++) acc[dt][reg] *= alpha[reg];
    // PV: O_strip += P_strip(16x64) @ V(64x64)  (P strip-local in LDS)
    short8 ap0 = *(const short8*)&Ps[(w * 16 + l15) * 72 + quad * 8];
    short8 ap1 = *(const short8*)&Ps[(w * 16 + l15) * 72 + 32 + quad * 8];
    #pragma unroll
    for (int dt = 0; dt < 4; dt++) {
      short8 bv0 = *(const short8*)&Vs[(dt * 16 + l15) * 72 + quad * 8];
      short8 bv1 = *(const short8*)&Vs[(dt * 16 + l15) * 72 + 32 + quad * 8];
      acc[dt] = __builtin_amdgcn_mfma_f32_16x16x32_bf16(ap0, bv0, acc[dt], 0, 0, 0);
      acc[dt] = __builtin_amdgcn_mfma_f32_16x16x32_bf16(ap1, bv1, acc[dt], 0, 0, 0);
    }
    __syncthreads();  // protect Ks/Vs before next staging
  }
  #pragma unroll
  for (int reg = 0; reg < 4; reg++) {
    float inv = 1.0f / l_i[reg];
    int row = bb * 2048 + qt * 64 + w * 16 + quad * 4 + reg;
    #pragma unroll
    for (int dt = 0; dt < 4; dt++)
      attn_out[(size_t)row * 1024 + h * 64 + dt * 16 + l15] = f2b(acc[dt][reg] * inv);
  }
}

extern "C" void kernel_launch(void* const* d_in, const int* in_sizes, int n_in,
                              void* d_out, int out_size, void* d_ws, size_t ws_size,
                              hipStream_t stream) {
  const float* x     = (const float*)d_in[0];
  const float* mask  = (const float*)d_in[1];
  const float* ln_g  = (const float*)d_in[2];
  const float* ln_b  = (const float*)d_in[3];
  const float* w_qkv = (const float*)d_in[4];
  const float* b_qkv = (const float*)d_in[5];
  const float* in_w  = (const float*)d_in[6];
  const float* in_b  = (const float*)d_in[7];
  const float* out_w = (const float*)d_in[8];
  const float* out_b = (const float*)d_in[9];
  float* out = (float*)d_out;
  char* ws = (char*)d_ws;

  // bf16 workspace layout (bytes), total 90.2 MB:
  u16* wqkv_b = (u16*)(ws);                  //  6291456  (3072x1024)
  u16* inw_b  = (u16*)(ws + 6291456ull);     //  6291456  (3072x1024)
  u16* outw_b = (u16*)(ws + 12582912ull);    //  2097152  (1024x1024)
  u16* xn_b   = (u16*)(ws + 14680064ull);    //  8388608  (4096x1024)
  u16* qkv_b  = (u16*)(ws + 23068672ull);    // 25165824  (4096x3072)
  u16* qkv2_b = (u16*)(ws + 48234496ull);    // 25165824  (4096x3072)
  u16* vT     = (u16*)(ws + 73400320ull);    //  8388608  (2,16,64,2048)
  u16* attn_b = (u16*)(ws + 81788928ull);    //  8388608  (4096x1024)

  pack_bf16<<<3072, 256, 0, stream>>>(w_qkv, wqkv_b, 786432);
  pack_bf16<<<3072, 256, 0, stream>>>(in_w, inw_b, 786432);
  pack_bf16<<<1024, 256, 0, stream>>>(out_w, outw_b, 262144);
  ln_pack<<<4096, 256, 0, stream>>>(x, ln_g, ln_b, xn_b);
  gemm_mfma<false, true><<<dim3(24, 32), 256, 0, stream>>>(
      xn_b, 1024, wqkv_b, b_qkv, nullptr, qkv_b, 3072, 1024);
  rope_b<<<16384, 256, 0, stream>>>(qkv_b);
  gemm_mfma<true, true><<<dim3(24, 32), 256, 0, stream>>>(
      qkv_b, 3072, inw_b, in_b, nullptr, qkv2_b, 3072, 1024);
  transpose_v<<<dim3(32, 16, 2), 256, 0, stream>>>(qkv2_b, vT);
  attn_mfma<<<dim3(16, 32, 2), 256, 0, stream>>>(qkv2_b, vT, mask, attn_b);
  gemm_mfma<false, false><<<dim3(8, 32), 256, 0, stream>>>(
      attn_b, 1024, outw_b, out_b, out, nullptr, 1024, 1024);
}

// Round 4
// 370.710 us; speedup vs baseline: 4.5183x; 1.5059x over previous
//
#include <hip/hip_runtime.h>

using u16 = unsigned short;
using u32 = unsigned int;
typedef __attribute__((ext_vector_type(8))) short short8;
typedef __attribute__((ext_vector_type(4))) float f32x4;

#define LOG2E 1.4426950408889634f
#define SCALE2 0.18033688011112042f  // 0.125 * log2(e)

__device__ __forceinline__ u16 f2b(float f) {  // RNE fp32->bf16
  union { float f; unsigned u; } v; v.f = f;
  unsigned r = v.u + 0x7fffu + ((v.u >> 16) & 1u);
  return (u16)(r >> 16);
}

typedef const __attribute__((address_space(1))) u32* gp_t;
typedef __attribute__((address_space(3))) u32* lp_t;
__device__ __forceinline__ void gl_lds16(const u16* g, u16* l) {
  __builtin_amdgcn_global_load_lds((gp_t)g, (lp_t)l, 16, 0, 0);
}

// ---------------- fp32 -> bf16 pack (weights) ----------------
__global__ __launch_bounds__(256) void pack_bf16(const float* __restrict__ in,
                                                 u16* __restrict__ out, int n4) {
  int i = blockIdx.x * 256 + threadIdx.x;
  if (i >= n4) return;
  float4 v = ((const float4*)in)[i];
  uint2 o;
  o.x = (unsigned)f2b(v.x) | ((unsigned)f2b(v.y) << 16);
  o.y = (unsigned)f2b(v.z) | ((unsigned)f2b(v.w) << 16);
  ((uint2*)out)[i] = o;
}

// ---------------- LayerNorm: x fp32 (4096,1024) -> xn bf16 ----------------
__global__ __launch_bounds__(256) void ln_pack(const float* __restrict__ x,
                                               const float* __restrict__ g,
                                               const float* __restrict__ beta,
                                               u16* __restrict__ xn) {
  int row = blockIdx.x;
  int t = threadIdx.x;
  const float* xr = x + (size_t)row * 1024;
  float4 v = *(const float4*)(xr + t * 4);
  float s = v.x + v.y + v.z + v.w;
  float ss = v.x * v.x + v.y * v.y + v.z * v.z + v.w * v.w;
  #pragma unroll
  for (int m = 1; m < 64; m <<= 1) {
    s  += __shfl_xor(s, m);
    ss += __shfl_xor(ss, m);
  }
  __shared__ float sbuf[4], ssbuf[4];
  int wave = t >> 6, lane = t & 63;
  if (lane == 0) { sbuf[wave] = s; ssbuf[wave] = ss; }
  __syncthreads();
  s  = sbuf[0] + sbuf[1] + sbuf[2] + sbuf[3];
  ss = ssbuf[0] + ssbuf[1] + ssbuf[2] + ssbuf[3];
  float mean = s * (1.0f / 1024.0f);
  float var  = ss * (1.0f / 1024.0f) - mean * mean;
  float rstd = 1.0f / sqrtf(var + 1e-5f);
  float4 gv = *(const float4*)(g + t * 4);
  float4 bv = *(const float4*)(beta + t * 4);
  uint2 o;
  o.x = (unsigned)f2b((v.x - mean) * rstd * gv.x + bv.x) |
        ((unsigned)f2b((v.y - mean) * rstd * gv.y + bv.y) << 16);
  o.y = (unsigned)f2b((v.z - mean) * rstd * gv.z + bv.z) |
        ((unsigned)f2b((v.w - mean) * rstd * gv.w + bv.w) << 16);
  *(uint2*)(xn + (size_t)row * 1024 + t * 4) = o;
}

// ---------------- RoPE cos/sin table: [pos(2048)][pair(512)] float2 ----------------
__global__ __launch_bounds__(256) void rope_tab(float2* __restrict__ tab) {
  int idx = blockIdx.x * 256 + threadIdx.x;   // 1048576
  int pos = idx >> 9, i = idx & 511;
  double ifreq = exp2(-(double)(2 * i) * (13.287712379549449 / 1024.0));
  double ang = (double)pos * ifreq;
  double sn, cs;
  sincos(ang, &sn, &cs);
  tab[idx] = make_float2((float)cs, (float)sn);
}

// ---------------- Mask pre-transform: fp32 (2,2048,2048) -> bf16*log2e in
// MFMA-fragment order [bb][qt][kt][w][quad][l15][nt][reg] ----------------
__global__ __launch_bounds__(256) void mask_prep(const float* __restrict__ mask,
                                                 u16* __restrict__ maskp) {
  int idx = blockIdx.x * 256 + threadIdx.x;   // 524288
  int l15 = idx & 15;
  int quad = (idx >> 4) & 3;
  int w = (idx >> 6) & 3;
  int kt = (idx >> 8) & 31;
  int qt = (idx >> 13) & 31;
  int bb = (idx >> 18) & 1;
  u16 vals[16];
  #pragma unroll
  for (int nt = 0; nt < 4; nt++)
    #pragma unroll
    for (int reg = 0; reg < 4; reg++) {
      float mv = mask[((size_t)bb * 2048 + qt * 64 + w * 16 + quad * 4 + reg) * 2048
                      + kt * 64 + nt * 16 + l15];
      vals[nt * 4 + reg] = f2b(mv * LOG2E);
    }
  uint4* dst = (uint4*)(maskp + (size_t)idx * 16);
  dst[0] = *(uint4*)&vals[0];
  dst[1] = *(uint4*)&vals[8];
}

// ---------------- bf16 MFMA GEMM (m97 structure): C = A @ W^T + bias ----------------
// 128x128 tile, BK=64, global_load_lds width-16 staging, unpadded LDS (stride 64).
// SLAB: A column offset (n0/1024)*1024. ROPE: fused interleaved rotary on cols<2048.
template<bool SLAB, bool OUT_BF16, bool ROPE>
__global__ __launch_bounds__(256) void gemm_mfma(const u16* __restrict__ A, int lda,
                                                 const u16* __restrict__ W,
                                                 const float* __restrict__ bias,
                                                 const float2* __restrict__ rtab,
                                                 float* __restrict__ Cf,
                                                 u16* __restrict__ Cb,
                                                 int ldc, int K) {
  __shared__ u16 As[128 * 64];
  __shared__ u16 Bs[128 * 64];
  int n0 = blockIdx.x * 128, m0 = blockIdx.y * 128;
  int aoff = SLAB ? ((n0 >> 10) << 10) : 0;
  int tid = threadIdx.x;
  int lane = tid & 63, l15 = lane & 15, quad = lane >> 4;
  int w = tid >> 6, mw = w & 1, nw = w >> 1;
  const u16* Abase = A + (size_t)m0 * lda + aoff;
  const u16* Wbase = W + (size_t)n0 * K;
  int lrow = lane >> 3, lcol = (lane & 7) * 8;
  f32x4 acc[4][4];
  #pragma unroll
  for (int i = 0; i < 4; i++)
    #pragma unroll
    for (int j = 0; j < 4; j++) acc[i][j] = (f32x4){0.f, 0.f, 0.f, 0.f};

  for (int k0 = 0; k0 < K; k0 += 64) {
    __syncthreads();  // prior frag reads done before LDS overwrite
    #pragma unroll
    for (int c = 0; c < 4; c++) {
      int row = c * 32 + w * 8 + lrow;
      gl_lds16(Abase + (size_t)row * lda + k0 + lcol, &As[(c * 32 + w * 8) * 64]);
      gl_lds16(Wbase + (size_t)row * K   + k0 + lcol, &Bs[(c * 32 + w * 8) * 64]);
    }
    __syncthreads();  // drains vmcnt (global_load_lds) per barrier semantics
    #pragma unroll
    for (int kk = 0; kk < 64; kk += 32) {
      short8 af[4], bfr[4];
      #pragma unroll
      for (int mt = 0; mt < 4; mt++)
        af[mt] = *(const short8*)&As[(mw * 64 + mt * 16 + l15) * 64 + kk + quad * 8];
      #pragma unroll
      for (int nt = 0; nt < 4; nt++)
        bfr[nt] = *(const short8*)&Bs[(nw * 64 + nt * 16 + l15) * 64 + kk + quad * 8];
      #pragma unroll
      for (int mt = 0; mt < 4; mt++)
        #pragma unroll
        for (int nt = 0; nt < 4; nt++)
          acc[mt][nt] = __builtin_amdgcn_mfma_f32_16x16x32_bf16(
              af[mt], bfr[nt], acc[mt][nt], 0, 0, 0);
    }
  }
  int mb = m0 + mw * 64, nb = n0 + nw * 64;
  float bv[4];
  #pragma unroll
  for (int nt = 0; nt < 4; nt++) bv[nt] = bias[nb + nt * 16 + l15];
  #pragma unroll
  for (int mt = 0; mt < 4; mt++)
    #pragma unroll
    for (int nt = 0; nt < 4; nt++) {
      int col = nb + nt * 16 + l15;
      #pragma unroll
      for (int reg = 0; reg < 4; reg++) {
        int row = mb + mt * 16 + quad * 4 + reg;   // C/D: row=quad*4+reg, col=l15
        float val = acc[mt][nt][reg] + bv[nt];
        if (ROPE && col < 2048) {      // wave-uniform condition (16-col blocks)
          float pr = __shfl_xor(val, 1);
          float2 cs = rtab[(size_t)(row & 2047) * 512 + ((col & 1023) >> 1)];
          val = (col & 1) ? fmaf(val, cs.x, pr * cs.y)
                          : fmaf(val, cs.x, -pr * cs.y);
        }
        if (OUT_BF16) Cb[(size_t)row * ldc + col] = f2b(val);
        else          Cf[(size_t)row * ldc + col] = val;
      }
    }
}

// ---------------- V transpose: qkv2 v-cols -> vT[bb][h][d][s] bf16 ----------------
__global__ __launch_bounds__(256) void transpose_v(const u16* __restrict__ qkv2,
                                                   u16* __restrict__ vT) {
  __shared__ u16 T[64 * 72];
  int st = blockIdx.x, h = blockIdx.y, bb = blockIdx.z;
  int t = threadIdx.x;
  int r = t >> 2, c0 = (t & 3) * 16;
  const u16* src = qkv2 + (size_t)(bb * 2048 + st * 64 + r) * 3072 + 2048 + h * 64 + c0;
  *(uint4*)&T[r * 72 + c0]     = *(const uint4*)src;
  *(uint4*)&T[r * 72 + c0 + 8] = *(const uint4*)(src + 8);
  __syncthreads();
  int d = t >> 2, s0 = (t & 3) * 16;
  u16 tmp[16];
  #pragma unroll
  for (int j = 0; j < 16; j++) tmp[j] = T[(s0 + j) * 72 + d];
  u16* dst = vT + ((size_t)((bb * 16 + h) * 64 + d)) * 2048 + st * 64 + s0;
  *(uint4*)dst       = *(uint4*)&tmp[0];
  *(uint4*)(dst + 8) = *(uint4*)&tmp[8];
}

// ---------------- Flash attention, bf16 MFMA, fixed-base exp2 softmax ----------------
// Block (h, qt, bb); 4 waves; wave w owns Q rows [qt*64+w*16,+16).
// Unnormalized accumulate: O += P@V, l += sum(p); normalize once at the end.
__global__ __launch_bounds__(256) void attn_mfma(const u16* __restrict__ qkv2,
                                                 const u16* __restrict__ vT,
                                                 const u16* __restrict__ maskp,
                                                 u16* __restrict__ attn_out) {
  __shared__ u16 Ks[64 * 72];
  __shared__ u16 Vs[64 * 72];
  __shared__ u16 Ps[64 * 72];
  int h = blockIdx.x, qt = blockIdx.y, bb = blockIdx.z;
  int tid = threadIdx.x;
  int lane = tid & 63, l15 = lane & 15, quad = lane >> 4;
  int w = tid >> 6;
  {  // stage Q (wave-local rows)
    int r = tid >> 2, c0 = (tid & 3) * 16;
    const u16* src = qkv2 + (size_t)(bb * 2048 + qt * 64 + r) * 3072 + h * 64 + c0;
    *(uint4*)&Ps[r * 72 + c0]     = *(const uint4*)src;
    *(uint4*)&Ps[r * 72 + c0 + 8] = *(const uint4*)(src + 8);
  }
  short8 aq0 = *(const short8*)&Ps[(w * 16 + l15) * 72 + quad * 8];
  short8 aq1 = *(const short8*)&Ps[(w * 16 + l15) * 72 + 32 + quad * 8];
  float lsum[4] = {0.f, 0.f, 0.f, 0.f};
  f32x4 acc[4];
  #pragma unroll
  for (int i = 0; i < 4; i++) acc[i] = (f32x4){0.f, 0.f, 0.f, 0.f};
  const u16* mbase = maskp + (((size_t)(bb * 32 + qt)) * 32) * 4096
                     + ((w * 4 + quad) * 16 + l15) * 16;
  for (int kt = 0; kt < 32; kt++) {
    {  // stage K tile and V^T tile
      int r = tid >> 2, c0 = (tid & 3) * 16;
      const u16* ksrc = qkv2 + (size_t)(bb * 2048 + kt * 64 + r) * 3072 + 1024 + h * 64 + c0;
      *(uint4*)&Ks[r * 72 + c0]     = *(const uint4*)ksrc;
      *(uint4*)&Ks[r * 72 + c0 + 8] = *(const uint4*)(ksrc + 8);
      const u16* vsrc = vT + ((size_t)((bb * 16 + h) * 64 + r)) * 2048 + kt * 64 + c0;
      *(uint4*)&Vs[r * 72 + c0]     = *(const uint4*)vsrc;
      *(uint4*)&Vs[r * 72 + c0 + 8] = *(const uint4*)(vsrc + 8);
    }
    // mask fragment load (L2-resident, coalesced 32B/lane)
    const uint4* mq = (const uint4*)(mbase + (size_t)kt * 4096);
    uint4 ma = mq[0], mb2 = mq[1];
    __syncthreads();
    // S = Q K^T
    f32x4 s[4];
    #pragma unroll
    for (int nt = 0; nt < 4; nt++) {
      short8 bk0 = *(const short8*)&Ks[(nt * 16 + l15) * 72 + quad * 8];
      short8 bk1 = *(const short8*)&Ks[(nt * 16 + l15) * 72 + 32 + quad * 8];
      f32x4 z = (f32x4){0.f, 0.f, 0.f, 0.f};
      z = __builtin_amdgcn_mfma_f32_16x16x32_bf16(aq0, bk0, z, 0, 0, 0);
      s[nt] = __builtin_amdgcn_mfma_f32_16x16x32_bf16(aq1, bk1, z, 0, 0, 0);
    }
    // unpack mask: vals[j] at word j>>1, half j&1 ; j = nt*4+reg
    u32 wds[8] = {ma.x, ma.y, ma.z, ma.w, mb2.x, mb2.y, mb2.z, mb2.w};
    float mv[16];
    #pragma unroll
    for (int j = 0; j < 8; j++) {
      mv[2 * j]     = __uint_as_float(wds[j] << 16);
      mv[2 * j + 1] = __uint_as_float(wds[j] & 0xffff0000u);
    }
    // p = 2^(qk*scale2 + mask*log2e); no max subtraction (bounded exponent)
    #pragma unroll
    for (int nt = 0; nt < 4; nt++)
      #pragma unroll
      for (int reg = 0; reg < 4; reg++) {
        float sv = fmaf(s[nt][reg], SCALE2, mv[nt * 4 + reg]);
        float p = __builtin_amdgcn_exp2f(sv);
        lsum[reg] += p;
        Ps[(w * 16 + quad * 4 + reg) * 72 + nt * 16 + l15] =
            (u16)((__float_as_uint(p) + 0x8000u) >> 16);  // RN pack
      }
    // PV: O_strip += P_strip(16x64) @ V(64x64)
    short8 ap0 = *(const short8*)&Ps[(w * 16 + l15) * 72 + quad * 8];
    short8 ap1 = *(const short8*)&Ps[(w * 16 + l15) * 72 + 32 + quad * 8];
    #pragma unroll
    for (int dt = 0; dt < 4; dt++) {
      short8 bv0 = *(const short8*)&Vs[(dt * 16 + l15) * 72 + quad * 8];
      short8 bv1 = *(const short8*)&Vs[(dt * 16 + l15) * 72 + 32 + quad * 8];
      acc[dt] = __builtin_amdgcn_mfma_f32_16x16x32_bf16(ap0, bv0, acc[dt], 0, 0, 0);
      acc[dt] = __builtin_amdgcn_mfma_f32_16x16x32_bf16(ap1, bv1, acc[dt], 0, 0, 0);
    }
    __syncthreads();  // protect Ks/Vs before next staging
  }
  #pragma unroll
  for (int reg = 0; reg < 4; reg++) {
    float l = lsum[reg];
    l += __shfl_xor(l, 1); l += __shfl_xor(l, 2);
    l += __shfl_xor(l, 4); l += __shfl_xor(l, 8);
    float inv = 1.0f / l;
    int row = bb * 2048 + qt * 64 + w * 16 + quad * 4 + reg;
    #pragma unroll
    for (int dt = 0; dt < 4; dt++)
      attn_out[(size_t)row * 1024 + h * 64 + dt * 16 + l15] = f2b(acc[dt][reg] * inv);
  }
}

extern "C" void kernel_launch(void* const* d_in, const int* in_sizes, int n_in,
                              void* d_out, int out_size, void* d_ws, size_t ws_size,
                              hipStream_t stream) {
  const float* x     = (const float*)d_in[0];
  const float* mask  = (const float*)d_in[1];
  const float* ln_g  = (const float*)d_in[2];
  const float* ln_b  = (const float*)d_in[3];
  const float* w_qkv = (const float*)d_in[4];
  const float* b_qkv = (const float*)d_in[5];
  const float* in_w  = (const float*)d_in[6];
  const float* in_b  = (const float*)d_in[7];
  const float* out_w = (const float*)d_in[8];
  const float* out_b = (const float*)d_in[9];
  float* out = (float*)d_out;
  char* ws = (char*)d_ws;

  // workspace layout (bytes), peak 98.6 MB:
  u16* wqkv_b = (u16*)(ws);                   //  6291456  (3072x1024)
  u16* inw_b  = (u16*)(ws + 6291456ull);      //  6291456  (3072x1024)
  u16* outw_b = (u16*)(ws + 12582912ull);     //  2097152  (1024x1024)
  u16* xn_b   = (u16*)(ws + 14680064ull);     //  8388608  (4096x1024)
  u16* attn_b = xn_b;                         //  reuse (xn dead after gemm1)
  u16* qkv_b  = (u16*)(ws + 23068672ull);     // 25165824  (4096x3072)
  u16* qkv2_b = (u16*)(ws + 48234496ull);     // 25165824  (4096x3072)
  float2* rtab = (float2*)qkv2_b;             //  8388608  aliases qkv2 (dead before gemm2)
  u16* vT     = (u16*)(ws + 73400320ull);     //  8388608  (2,16,64,2048)
  u16* maskp  = (u16*)(ws + 81788928ull);     // 16777216  (524288*16 bf16)

  pack_bf16<<<3072, 256, 0, stream>>>(w_qkv, wqkv_b, 786432);
  pack_bf16<<<3072, 256, 0, stream>>>(in_w, inw_b, 786432);
  pack_bf16<<<1024, 256, 0, stream>>>(out_w, outw_b, 262144);
  ln_pack<<<4096, 256, 0, stream>>>(x, ln_g, ln_b, xn_b);
  rope_tab<<<4096, 256, 0, stream>>>(rtab);
  mask_prep<<<2048, 256, 0, stream>>>(mask, maskp);
  gemm_mfma<false, true, true><<<dim3(24, 32), 256, 0, stream>>>(
      xn_b, 1024, wqkv_b, b_qkv, rtab, nullptr, qkv_b, 3072, 1024);
  gemm_mfma<true, true, false><<<dim3(24, 32), 256, 0, stream>>>(
      qkv_b, 3072, inw_b, in_b, nullptr, nullptr, qkv2_b, 3072, 1024);
  transpose_v<<<dim3(32, 16, 2), 256, 0, stream>>>(qkv2_b, vT);
  attn_mfma<<<dim3(16, 32, 2), 256, 0, stream>>>(qkv2_b, vT, maskp, attn_b);
  gemm_mfma<false, false, false><<<dim3(8, 32), 256, 0, stream>>>(
      attn_b, 1024, outw_b, out_b, nullptr, out, nullptr, 1024, 1024);
}